// Round 6
// baseline (314.033 us; speedup 1.0000x reference)
//
#include <hip/hip_runtime.h>

// VQ layer, two-pass certified scheme.
// score(t,k) = z_t.e_k - 0.5||e_k||^2 ; argmax_k == argmin_k ||z_t-e_k||^2.
//
// Pass 1 (MFMA, fp16x2 3-term): x=h1+h2 (fp16), keep h1g1+h1g2+h2g1.
//   Worst-case score error eps <= 1.1e-3 (dropped h2g2 <= 2^-24*||z||*||e||,
//   split residual 3e-5, hyper-paranoid fp32 accum 1e-3). Track top-2 per
//   token; gap >= DELTA=5e-3 > 2*eps certifies the winner == true argmin.
// Pass 2 (exact fp32 repair): uncertain tokens -> ws list (atomic append);
//   one wave per token recomputes all 4096 exact scores, rewrites output.
//
// d_ws: [0,1MB)           emb B-fragments, fp16 2-level, frag-linear
//       [1MB,+16KB)       0.5*||e||^2 fp32 per code
//       [OFF_CNT]         u32 uncertain counter (init by pack kernel)
//       [OFF_LIST,+256KB) u32 uncertain-token list
// Fallback to pure-fp32 kernel if ws_size too small.

typedef __attribute__((ext_vector_type(8))) short    short8;
typedef __attribute__((ext_vector_type(8))) _Float16 half8;
typedef __attribute__((ext_vector_type(4))) float    f32x4;
typedef unsigned int u32;
typedef __attribute__((address_space(3))) u32 lds_u32;
typedef const __attribute__((address_space(1))) u32 glb_u32;

#define NCHUNK 256                        // 4096 codes / 16 per chunk
#define GROUP 4                           // chunks staged per barrier
#define NGROUP 64
#define FRAGS 4                           // 2 levels x 2 K-halves
#define CHUNK_BYTES (FRAGS * 64 * 16)     // 4096
#define GROUP_BYTES (GROUP * CHUNK_BYTES) // 16384
#define WSB_BYTES (NCHUNK * CHUNK_BYTES)  // 1 MB
#define OFF_N    WSB_BYTES
#define OFF_CNT  (OFF_N + 16384)
#define OFF_LIST (OFF_CNT + 64)
#define WS_NEEDED ((size_t)OFF_LIST + 65536u * 4u)   // ~1.33 MB
#define DELTA 0.005f

// ---- prep: pack emb into 2-level fp16 B-fragments + norms + counter ------
// 16B-group id = (ck*4 + f)*64 + lane;  f = level*2 + s (s = K-half).
// B-frag (16x16x32): n = lane&15, k = s*32 + (lane>>4)*8 + j.
__global__ void vq_pack_kernel(const float* __restrict__ emb,
                               unsigned short* __restrict__ wsB,
                               float* __restrict__ wsN,
                               u32* __restrict__ wsCnt) {
    int ck    = blockIdx.x;              // 256 blocks x 256 threads
    int f     = threadIdx.x >> 6;
    int lane  = threadIdx.x & 63;
    int level = f >> 1, s = f & 1;
    int code  = ck * 16 + (lane & 15);
    int kb    = s * 32 + (lane >> 4) * 8;
    const float* src = emb + code * 64 + kb;
    short8 o;
#pragma unroll
    for (int j = 0; j < 8; ++j) {
        float x = src[j];
        _Float16 h1 = (_Float16)x;                 // RNE
        _Float16 h2 = (_Float16)(x - (float)h1);
        o[j] = __builtin_bit_cast(short, level == 0 ? h1 : h2);
    }
    ((short8*)wsB)[(ck * FRAGS + f) * 64 + lane] = o;

    if (threadIdx.x < 16) {                        // exact fp32 half-norms
        int c = ck * 16 + threadIdx.x;
        const float* e = emb + c * 64;
        float ssum = 0.f;
#pragma unroll
        for (int k = 0; k < 64; ++k) { float v = e[k]; ssum = fmaf(v, v, ssum); }
        wsN[c] = 0.5f * ssum;
    }
    if (ck == 0 && threadIdx.x == 0) *wsCnt = 0u;  // list counter init
}

// ---- pass 1: MFMA approx scores + top-2 certification --------------------
// 512 blocks x 256 threads (4 waves); block owns 128 tokens, wave owns 32.
__global__ __launch_bounds__(256, 2) void vq_main_kernel(
    const float* __restrict__ z, const float* __restrict__ emb,
    const unsigned short* __restrict__ wsB, const float* __restrict__ wsN,
    u32* __restrict__ wsCnt, u32* __restrict__ wsList,
    float* __restrict__ out)
{
    __shared__ char  sB[2][GROUP_BYTES];  // 2 x 16 KB double buffer
    __shared__ float sN[2][64];           // staged 0.5||e||^2 per group
    __shared__ int   sBest[128];

    const int wave = threadIdx.x >> 6;
    const int lane = threadIdx.x & 63;
    const int quad = lane >> 4;
    const int col  = lane & 15;

    const int t0 = blockIdx.x * 128 + wave * 32;

    // A fragments, fp16 2-level: a[tile][level][half], k = half*32+quad*8+j
    half8 a[2][2][2];
#pragma unroll
    for (int t = 0; t < 2; ++t) {
        const int tok = t0 + t * 16 + col;
        const int b   = tok >> 12;
        const int hw  = tok & 4095;
        const float* zp = z + b * 262144 + hw;
#pragma unroll
        for (int s = 0; s < 2; ++s)
#pragma unroll
            for (int j = 0; j < 8; ++j) {
                int k = s * 32 + quad * 8 + j;
                float x = zp[k * 4096];            // coalesced over col lanes
                _Float16 h1 = (_Float16)x;
                a[t][0][s][j] = h1;
                a[t][1][s][j] = (_Float16)(x - (float)h1);
            }
    }

    float best[2][4], best2[2][4];
    int   bidx[2][4];
#pragma unroll
    for (int t = 0; t < 2; ++t)
#pragma unroll
        for (int r = 0; r < 4; ++r) {
            best[t][r] = -3.4e38f; best2[t][r] = -3.4e38f; bidx[t][r] = 0;
        }

    // async stage one 16 KB group: wave w copies chunk w (4 KB = four 1 KB
    // ops, dst = uniform base + lane*16). Wave 0 also stages 64 norms.
    auto stage = [&](int buf, int g) {
        const char* gbase = ((const char*)wsB) + g * GROUP_BYTES + wave * CHUNK_BYTES;
        char*       lbase = sB[buf] + wave * CHUNK_BYTES;
#pragma unroll
        for (int i = 0; i < 4; ++i)
            __builtin_amdgcn_global_load_lds(
                (glb_u32*)(gbase + i * 1024 + lane * 16),
                (lds_u32*)(lbase + i * 1024), 16, 0, 0);
        if (wave == 0)
            __builtin_amdgcn_global_load_lds(
                (glb_u32*)(wsN + g * 64 + lane),
                (lds_u32*)&sN[buf][0], 4, 0, 0);
    };

    stage(0, 0);

    for (int g = 0; g < NGROUP; ++g) {
        const int cur = g & 1;
        __syncthreads();                  // own vmcnt drained, all waves here
        if (g + 1 < NGROUP) stage(cur ^ 1, g + 1);

#pragma unroll
        for (int cl = 0; cl < GROUP; ++cl) {
            const int ck = g * GROUP + cl;
            const char* base = sB[cur] + cl * CHUNK_BYTES;
            // lane-contiguous b128 reads: conflict-free
            half8 b10 = __builtin_bit_cast(half8, ((const short8*)(base + 0 * 1024))[lane]); // g1 h0
            half8 b11 = __builtin_bit_cast(half8, ((const short8*)(base + 1 * 1024))[lane]); // g1 h1
            half8 b20 = __builtin_bit_cast(half8, ((const short8*)(base + 2 * 1024))[lane]); // g2 h0
            half8 b21 = __builtin_bit_cast(half8, ((const short8*)(base + 3 * 1024))[lane]); // g2 h1
            const float nrm  = sN[cur][cl * 16 + col];
            const int   code = ck * 16 + col;  // C/D: col=lane&15, row=quad*4+r

#pragma unroll
            for (int t = 0; t < 2; ++t) {
                f32x4 acc = {0.f, 0.f, 0.f, 0.f};
                // small terms first (2^-12): h2g1, h1g2; then main h1g1
                acc = __builtin_amdgcn_mfma_f32_16x16x32_f16(a[t][1][0], b10, acc, 0, 0, 0);
                acc = __builtin_amdgcn_mfma_f32_16x16x32_f16(a[t][1][1], b11, acc, 0, 0, 0);
                acc = __builtin_amdgcn_mfma_f32_16x16x32_f16(a[t][0][0], b20, acc, 0, 0, 0);
                acc = __builtin_amdgcn_mfma_f32_16x16x32_f16(a[t][0][1], b21, acc, 0, 0, 0);
                acc = __builtin_amdgcn_mfma_f32_16x16x32_f16(a[t][0][0], b10, acc, 0, 0, 0);
                acc = __builtin_amdgcn_mfma_f32_16x16x32_f16(a[t][0][1], b11, acc, 0, 0, 0);

#pragma unroll
                for (int r = 0; r < 4; ++r) {
                    float sc  = acc[r] - nrm;
                    bool  gt1 = sc > best[t][r];
                    best2[t][r] = gt1 ? best[t][r] : fmaxf(sc, best2[t][r]);
                    if (gt1) { best[t][r] = sc; bidx[t][r] = code; }
                }
            }
        }
    }

    // top-2 merge across the 16 cols of each quad group; ties -> gap 0
#pragma unroll
    for (int off = 1; off < 16; off <<= 1)
#pragma unroll
        for (int t = 0; t < 2; ++t)
#pragma unroll
            for (int r = 0; r < 4; ++r) {
                float os1 = __shfl_xor(best[t][r],  off, 64);
                int   oi1 = __shfl_xor(bidx[t][r],  off, 64);
                float os2 = __shfl_xor(best2[t][r], off, 64);
                bool take = (os1 > best[t][r]) ||
                            (os1 == best[t][r] && oi1 < bidx[t][r]);
                float ns2 = take ? fmaxf(best[t][r], os2)
                                 : fmaxf(best2[t][r], os1);
                if (take) { best[t][r] = os1; bidx[t][r] = oi1; }
                best2[t][r] = ns2;
            }
    if (col == 0)
#pragma unroll
        for (int t = 0; t < 2; ++t)
#pragma unroll
            for (int r = 0; r < 4; ++r) {
                int tokb = wave * 32 + t * 16 + quad * 4 + r;
                sBest[tokb] = bidx[t][r];
                if (best[t][r] - best2[t][r] < DELTA) {   // uncertain
                    u32 slot = atomicAdd(wsCnt, 1u);
                    wsList[slot] = (u32)(blockIdx.x * 128 + tokb);
                }
            }
    __syncthreads();

    // output: 128 tokens x 64 c; lanes = consecutive tokens -> coalesced
    const int tk   = threadIdx.x & 127;
    const int coff = (threadIdx.x >> 7) * 32;
    const int gt   = blockIdx.x * 128 + tk;
    const int ob   = gt >> 12, ohw = gt & 4095;
    float* op = out + ob * 262144 + ohw;
    const float4* ep = (const float4*)(emb + sBest[tk] * 64 + coff);
#pragma unroll
    for (int i = 0; i < 8; ++i) {
        float4 v = ep[i];
        op[(coff + 4 * i + 0) * 4096] = v.x;
        op[(coff + 4 * i + 1) * 4096] = v.y;
        op[(coff + 4 * i + 2) * 4096] = v.z;
        op[(coff + 4 * i + 3) * 4096] = v.w;
    }
}

// ---- pass 2: exact fp32 repair of uncertain tokens -----------------------
// 256 blocks x 256 threads = 1024 waves; one wave per uncertain token.
__global__ __launch_bounds__(256) void vq_fix_kernel(
    const float* __restrict__ z, const float* __restrict__ emb,
    const float* __restrict__ wsN, const u32* __restrict__ wsCnt,
    const u32* __restrict__ wsList, float* __restrict__ out)
{
    const int nw   = gridDim.x * 4;
    const int wid  = blockIdx.x * 4 + (threadIdx.x >> 6);
    const int lane = threadIdx.x & 63;
    const u32 count = *wsCnt;

    for (u32 u = wid; u < count; u += nw) {
        const int t  = (int)wsList[u];
        const int b  = t >> 12, hw = t & 4095;
        const float* zp = z + b * 262144 + hw;
        float zf[64];
#pragma unroll
        for (int c = 0; c < 64; ++c) zf[c] = zp[c * 4096];  // lane-broadcast

        float best = -3.4e38f; int bi = 0;
        for (int k = lane; k < 4096; k += 64) {             // ascending/lane
            const float* e = emb + k * 64;
            float dot = 0.f;
#pragma unroll
            for (int c = 0; c < 64; ++c) dot = fmaf(zf[c], e[c], dot);
            float score = dot - wsN[k];
            if (score > best) { best = score; bi = k; }
        }
#pragma unroll
        for (int off = 1; off < 64; off <<= 1) {
            float os = __shfl_xor(best, off, 64);
            int   oi = __shfl_xor(bi,   off, 64);
            if (os > best || (os == best && oi < bi)) { best = os; bi = oi; }
        }
        out[b * 262144 + lane * 4096 + hw] = emb[bi * 64 + lane];
    }
}

// ---- fallback (proven Round-1 kernel; used only if ws is too small) ------
__global__ __launch_bounds__(256) void vq_fp32_kernel(
    const float* __restrict__ z, const float* __restrict__ emb,
    float* __restrict__ out)
{
    __shared__ float se[64 * 64];
    __shared__ float snorm[64];

    const int t  = blockIdx.x * 256 + threadIdx.x;
    const int b  = t >> 12;
    const int hw = t & 4095;
    const float* zt = z + (size_t)b * 262144 + hw;
    float zf[64];
#pragma unroll
    for (int c = 0; c < 64; ++c) zf[c] = zt[(size_t)c * 4096];

    float best = -3.4e38f;
    int   bestIdx = 0;
    for (int k0 = 0; k0 < 4096; k0 += 64) {
        __syncthreads();
        const float4* src = (const float4*)(emb + (size_t)k0 * 64);
        float4*       dst = (float4*)se;
#pragma unroll
        for (int i = 0; i < 4; ++i)
            dst[i * 256 + threadIdx.x] = src[i * 256 + threadIdx.x];
        __syncthreads();
        if (threadIdx.x < 64) {
            float s = 0.f;
#pragma unroll
            for (int c = 0; c < 64; ++c) {
                float v = se[threadIdx.x * 64 + c];
                s = fmaf(v, v, s);
            }
            snorm[threadIdx.x] = 0.5f * s;
        }
        __syncthreads();
#pragma unroll 4
        for (int kk = 0; kk < 64; ++kk) {
            float dot = 0.f;
#pragma unroll
            for (int c = 0; c < 64; ++c)
                dot = fmaf(zf[c], se[kk * 64 + c], dot);
            float score = dot - snorm[kk];
            if (score > best) { best = score; bestIdx = k0 + kk; }
        }
    }
    const float* e  = emb + (size_t)bestIdx * 64;
    float*       ot = out + (size_t)b * 262144 + hw;
#pragma unroll
    for (int c = 0; c < 64; ++c) ot[(size_t)c * 4096] = e[c];
}

extern "C" void kernel_launch(void* const* d_in, const int* in_sizes, int n_in,
                              void* d_out, int out_size, void* d_ws, size_t ws_size,
                              hipStream_t stream) {
    const float* z   = (const float*)d_in[0];
    const float* emb = (const float*)d_in[1];
    float*       out = (float*)d_out;

    if (ws_size < WS_NEEDED) {          // constant per session: graph-safe
        vq_fp32_kernel<<<256, 256, 0, stream>>>(z, emb, out);
        return;
    }

    unsigned short* wsB   = (unsigned short*)d_ws;
    float*          wsN   = (float*)((char*)d_ws + OFF_N);
    u32*            wsCnt = (u32*)((char*)d_ws + OFF_CNT);
    u32*            wsList= (u32*)((char*)d_ws + OFF_LIST);

    vq_pack_kernel<<<256, 256, 0, stream>>>(emb, wsB, wsN, wsCnt);
    vq_main_kernel<<<512, 256, 0, stream>>>(z, emb, wsB, wsN, wsCnt, wsList, out);
    vq_fix_kernel<<<256, 256, 0, stream>>>(z, emb, wsN, wsCnt, wsList, out);
}

// Round 7
// 239.406 us; speedup vs baseline: 1.3117x; 1.3117x over previous
//
#include <hip/hip_runtime.h>

// VQ layer, two-pass certified scheme, single bf16x3 packed codebook.
// score(t,k) = z_t.e_k - 0.5||e_k||^2 ; argmax_k == argmin_k ||z_t-e_k||^2.
//
// Pass 1 (MFMA, bf16x2 3-term): x=h1+h2, keep h1g1+h1g2+h2g1.
//   eps_hard <= ~3e-4. Top-2 per token; gap >= DELTA=5e-3 (16x margin)
//   certifies the winner == true fp32 argmin.
// Pass 2 (MFMA, bf16x3 6-term == Round-5 numerics, absmax 0.0 proven):
//   uncertain tokens gathered into 16-token tiles; block per tile, 4 waves
//   split the codebook; B-frags read coalesced from packed ws.
//
// d_ws: [0,1.5MB)        emb B-fragments, bf16 3-level, frag-linear
//       [OFF_N,+16KB)    0.5*||e||^2 fp32 per code
//       [OFF_CNT]        u32 uncertain counter (init by pack kernel)
//       [OFF_LIST,+256KB) u32 uncertain-token list (capacity 65536 = max)
// Fallback to pure-fp32 kernel if ws_size too small.

typedef __attribute__((ext_vector_type(8))) short short8;
typedef __attribute__((ext_vector_type(4))) float f32x4;
typedef unsigned int u32;
typedef __attribute__((address_space(3))) u32 lds_u32;
typedef const __attribute__((address_space(1))) u32 glb_u32;

#define NCHUNK 256                         // 4096 codes / 16 per chunk
#define GROUP 4                            // chunks staged per barrier (pass 1)
#define NGROUP 64
#define FRAGS 6                            // 3 levels x 2 K-halves
#define CHUNK_WSB (FRAGS * 64 * 16)        // 6144 B per chunk in ws
#define CHUNK_LDS 4096                     // levels 1-2 only staged in pass 1
#define GROUP_BYTES (GROUP * CHUNK_LDS)    // 16 KB
#define WSB_BYTES (NCHUNK * CHUNK_WSB)     // 1,572,864
#define OFF_N    WSB_BYTES
#define OFF_CNT  (OFF_N + 16384)
#define OFF_LIST (OFF_CNT + 64)
#define WS_NEEDED ((size_t)OFF_LIST + 65536u * 4u)   // ~1.77 MB
#define DELTA 0.005f

static __device__ __forceinline__ unsigned short f2bf(float f) {
    u32 u = __builtin_bit_cast(u32, f);
    u += 0x7fffu + ((u >> 16) & 1u);       // RNE; inputs finite Gaussians
    return (unsigned short)(u >> 16);
}
static __device__ __forceinline__ float bf2f(unsigned short h) {
    u32 u = ((u32)h) << 16;
    return __builtin_bit_cast(float, u);
}

// ---- prep: pack emb into 3-level bf16 B-fragments + norms + counter ------
// 16B-group id = (ck*6 + f)*64 + lane;  f = level*2 + s (s = K-half).
// B-frag (16x16x32): n = lane&15, k = s*32 + (lane>>4)*8 + j.
// 256 blocks (one per chunk) x 384 threads (6 frags x 64 lanes).
__global__ void vq_pack_kernel(const float* __restrict__ emb,
                               unsigned short* __restrict__ wsB,
                               float* __restrict__ wsN,
                               u32* __restrict__ wsCnt) {
    int ck    = blockIdx.x;
    int f     = threadIdx.x >> 6;
    int lane  = threadIdx.x & 63;
    int level = f >> 1, s = f & 1;
    int code  = ck * 16 + (lane & 15);
    int kb    = s * 32 + (lane >> 4) * 8;
    const float* src = emb + code * 64 + kb;
    short8 o;
#pragma unroll
    for (int j = 0; j < 8; ++j) {
        float x = src[j];
        unsigned short h1 = f2bf(x);
        float r1 = x - bf2f(h1);
        unsigned short h2 = f2bf(r1);
        float r2 = r1 - bf2f(h2);
        unsigned short h3 = f2bf(r2);
        o[j] = (short)(level == 0 ? h1 : (level == 1 ? h2 : h3));
    }
    ((short8*)wsB)[(ck * FRAGS + f) * 64 + lane] = o;

    if (threadIdx.x < 16) {                // exact fp32 half-norms
        int c = ck * 16 + threadIdx.x;
        const float* e = emb + c * 64;
        float ssum = 0.f;
#pragma unroll
        for (int k = 0; k < 64; ++k) { float v = e[k]; ssum = fmaf(v, v, ssum); }
        wsN[c] = 0.5f * ssum;
    }
    if (ck == 0 && threadIdx.x == 0) *wsCnt = 0u;
}

// ---- pass 1: bf16x2 3-term MFMA + top-2 certification --------------------
// 512 blocks x 256 threads (4 waves); block owns 128 tokens, wave owns 32.
__global__ __launch_bounds__(256, 2) void vq_main_kernel(
    const float* __restrict__ z, const float* __restrict__ emb,
    const unsigned short* __restrict__ wsB, const float* __restrict__ wsN,
    u32* __restrict__ wsCnt, u32* __restrict__ wsList,
    float* __restrict__ out)
{
    __shared__ char  sB[2][GROUP_BYTES];   // 2 x 16 KB double buffer
    __shared__ float sN[2][64];            // staged 0.5||e||^2 per group
    __shared__ int   sBest[128];

    const int wave = threadIdx.x >> 6;
    const int lane = threadIdx.x & 63;
    const int quad = lane >> 4;
    const int col  = lane & 15;

    const int t0 = blockIdx.x * 128 + wave * 32;

    // A fragments, bf16 2-level: a[tile][level][half], k = half*32+quad*8+j
    short8 a[2][2][2];
#pragma unroll
    for (int t = 0; t < 2; ++t) {
        const int tok = t0 + t * 16 + col;
        const int b   = tok >> 12;
        const int hw  = tok & 4095;
        const float* zp = z + b * 262144 + hw;
#pragma unroll
        for (int s = 0; s < 2; ++s)
#pragma unroll
            for (int j = 0; j < 8; ++j) {
                int k = s * 32 + quad * 8 + j;
                float x = zp[k * 4096];            // coalesced over col lanes
                unsigned short h1 = f2bf(x);
                a[t][0][s][j] = (short)h1;
                a[t][1][s][j] = (short)f2bf(x - bf2f(h1));
            }
    }

    float best[2][4], best2[2][4];
    int   bidx[2][4];
#pragma unroll
    for (int t = 0; t < 2; ++t)
#pragma unroll
        for (int r = 0; r < 4; ++r) {
            best[t][r] = -3.4e38f; best2[t][r] = -3.4e38f; bidx[t][r] = 0;
        }

    // async stage: wave w copies levels 1-2 (first 4 KB) of chunk g*4+w.
    auto stage = [&](int buf, int g) {
        const char* gbase = ((const char*)wsB) + (size_t)(g * GROUP + wave) * CHUNK_WSB;
        char*       lbase = sB[buf] + wave * CHUNK_LDS;
#pragma unroll
        for (int i = 0; i < 4; ++i)
            __builtin_amdgcn_global_load_lds(
                (glb_u32*)(gbase + i * 1024 + lane * 16),
                (lds_u32*)(lbase + i * 1024), 16, 0, 0);
        if (wave == 0)
            __builtin_amdgcn_global_load_lds(
                (glb_u32*)(wsN + g * 64 + lane),
                (lds_u32*)&sN[buf][0], 4, 0, 0);
    };

    stage(0, 0);

    for (int g = 0; g < NGROUP; ++g) {
        const int cur = g & 1;
        __syncthreads();                   // own vmcnt drained, all waves here
        if (g + 1 < NGROUP) stage(cur ^ 1, g + 1);

#pragma unroll
        for (int cl = 0; cl < GROUP; ++cl) {
            const int ck = g * GROUP + cl;
            const char* base = sB[cur] + cl * CHUNK_LDS;
            // lane-contiguous b128 reads: conflict-free
            short8 b10 = ((const short8*)(base + 0 * 1024))[lane]; // g1 h0
            short8 b11 = ((const short8*)(base + 1 * 1024))[lane]; // g1 h1
            short8 b20 = ((const short8*)(base + 2 * 1024))[lane]; // g2 h0
            short8 b21 = ((const short8*)(base + 3 * 1024))[lane]; // g2 h1
            const float nrm  = sN[cur][cl * 16 + col];
            const int   code = ck * 16 + col;  // C/D: col=lane&15, row=quad*4+r

#pragma unroll
            for (int t = 0; t < 2; ++t) {
                f32x4 acc = {0.f, 0.f, 0.f, 0.f};
                // small terms first (2^-9): h2g1, h1g2; then main h1g1
                acc = __builtin_amdgcn_mfma_f32_16x16x32_bf16(a[t][1][0], b10, acc, 0, 0, 0);
                acc = __builtin_amdgcn_mfma_f32_16x16x32_bf16(a[t][1][1], b11, acc, 0, 0, 0);
                acc = __builtin_amdgcn_mfma_f32_16x16x32_bf16(a[t][0][0], b20, acc, 0, 0, 0);
                acc = __builtin_amdgcn_mfma_f32_16x16x32_bf16(a[t][0][1], b21, acc, 0, 0, 0);
                acc = __builtin_amdgcn_mfma_f32_16x16x32_bf16(a[t][0][0], b10, acc, 0, 0, 0);
                acc = __builtin_amdgcn_mfma_f32_16x16x32_bf16(a[t][0][1], b11, acc, 0, 0, 0);

#pragma unroll
                for (int r = 0; r < 4; ++r) {
                    float sc  = acc[r] - nrm;
                    bool  gt1 = sc > best[t][r];
                    best2[t][r] = gt1 ? best[t][r] : fmaxf(sc, best2[t][r]);
                    if (gt1) { best[t][r] = sc; bidx[t][r] = code; }
                }
            }
        }
    }

    // top-2 merge across the 16 cols of each quad group
#pragma unroll
    for (int off = 1; off < 16; off <<= 1)
#pragma unroll
        for (int t = 0; t < 2; ++t)
#pragma unroll
            for (int r = 0; r < 4; ++r) {
                float os1 = __shfl_xor(best[t][r],  off, 64);
                int   oi1 = __shfl_xor(bidx[t][r],  off, 64);
                float os2 = __shfl_xor(best2[t][r], off, 64);
                bool take = (os1 > best[t][r]) ||
                            (os1 == best[t][r] && oi1 < bidx[t][r]);
                float ns2 = take ? fmaxf(best[t][r], os2)
                                 : fmaxf(best2[t][r], os1);
                if (take) { best[t][r] = os1; bidx[t][r] = oi1; }
                best2[t][r] = ns2;
            }
    if (col == 0)
#pragma unroll
        for (int t = 0; t < 2; ++t)
#pragma unroll
            for (int r = 0; r < 4; ++r) {
                int tokb = wave * 32 + t * 16 + quad * 4 + r;
                sBest[tokb] = bidx[t][r];
                if (best[t][r] - best2[t][r] < DELTA) {   // uncertain
                    u32 slot = atomicAdd(wsCnt, 1u);
                    wsList[slot] = (u32)(blockIdx.x * 128 + tokb);
                }
            }
    __syncthreads();

    // output: 128 tokens x 64 c; lanes = consecutive tokens -> coalesced
    const int tk   = threadIdx.x & 127;
    const int coff = (threadIdx.x >> 7) * 32;
    const int gt   = blockIdx.x * 128 + tk;
    const int ob   = gt >> 12, ohw = gt & 4095;
    float* op = out + ob * 262144 + ohw;
    const float4* ep = (const float4*)(emb + sBest[tk] * 64 + coff);
#pragma unroll
    for (int i = 0; i < 8; ++i) {
        float4 v = ep[i];
        op[(coff + 4 * i + 0) * 4096] = v.x;
        op[(coff + 4 * i + 1) * 4096] = v.y;
        op[(coff + 4 * i + 2) * 4096] = v.z;
        op[(coff + 4 * i + 3) * 4096] = v.w;
    }
}

// ---- pass 2: MFMA bf16x3 6-term repair (Round-5 numerics) ----------------
// 64 blocks x 256 threads; block processes one 16-token tile per iteration;
// wave w scores chunks [w*64, w*64+64) (1024 codes); B-frags read coalesced
// from packed ws (1 KB per b128 instruction).
__global__ __launch_bounds__(256) void vq_fix_kernel(
    const float* __restrict__ z, const float* __restrict__ emb,
    const unsigned short* __restrict__ wsB, const float* __restrict__ wsN,
    const u32* __restrict__ wsCnt, const u32* __restrict__ wsList,
    float* __restrict__ out)
{
    __shared__ float sS[4][16];
    __shared__ int   sI[4][16];
    __shared__ int   sTok[16];

    const int wave = threadIdx.x >> 6;
    const int lane = threadIdx.x & 63;
    const int quad = lane >> 4;
    const int col  = lane & 15;
    const u32 count = *wsCnt;
    const u32 tiles = (count + 15u) >> 4;

    for (u32 T = blockIdx.x; T < tiles; T += gridDim.x) {
        if (threadIdx.x < 16) {
            u32 slot = T * 16 + threadIdx.x;
            if (slot >= count) slot = count - 1;     // duplicates benign
            sTok[threadIdx.x] = (int)wsList[slot];
        }
        __syncthreads();

        // A fragments bf16x3 for this tile's 16 tokens
        const int tok = sTok[col];
        const int b   = tok >> 12;
        const int hw  = tok & 4095;
        const float* zp = z + b * 262144 + hw;
        short8 a[3][2];
#pragma unroll
        for (int s = 0; s < 2; ++s)
#pragma unroll
            for (int j = 0; j < 8; ++j) {
                int k = s * 32 + quad * 8 + j;
                float x = zp[k * 4096];
                unsigned short h1 = f2bf(x);
                float r1 = x - bf2f(h1);
                unsigned short h2 = f2bf(r1);
                float r2 = r1 - bf2f(h2);
                a[0][s][j] = (short)h1;
                a[1][s][j] = (short)h2;
                a[2][s][j] = (short)f2bf(r2);
            }

        float best[4] = {-3.4e38f, -3.4e38f, -3.4e38f, -3.4e38f};
        int   bidx[4] = {0, 0, 0, 0};

        const short8* Bg = (const short8*)wsB;
        for (int ck = wave * 64; ck < wave * 64 + 64; ++ck) {
            const int fb = ck * FRAGS * 64;          // frag base (short8 units)
            short8 b10 = Bg[fb + 0 * 64 + lane];     // coalesced 1 KB reads
            short8 b11 = Bg[fb + 1 * 64 + lane];
            short8 b20 = Bg[fb + 2 * 64 + lane];
            short8 b21 = Bg[fb + 3 * 64 + lane];
            short8 b30 = Bg[fb + 4 * 64 + lane];
            short8 b31 = Bg[fb + 5 * 64 + lane];
            const float nrm  = wsN[ck * 16 + col];
            const int   code = ck * 16 + col;

            f32x4 acc = {0.f, 0.f, 0.f, 0.f};
            // Round-5 proven order: 2^-18 terms, then 2^-9, then main
            acc = __builtin_amdgcn_mfma_f32_16x16x32_bf16(a[1][0], b20, acc, 0, 0, 0);
            acc = __builtin_amdgcn_mfma_f32_16x16x32_bf16(a[1][1], b21, acc, 0, 0, 0);
            acc = __builtin_amdgcn_mfma_f32_16x16x32_bf16(a[0][0], b30, acc, 0, 0, 0);
            acc = __builtin_amdgcn_mfma_f32_16x16x32_bf16(a[0][1], b31, acc, 0, 0, 0);
            acc = __builtin_amdgcn_mfma_f32_16x16x32_bf16(a[2][0], b10, acc, 0, 0, 0);
            acc = __builtin_amdgcn_mfma_f32_16x16x32_bf16(a[2][1], b11, acc, 0, 0, 0);
            acc = __builtin_amdgcn_mfma_f32_16x16x32_bf16(a[0][0], b20, acc, 0, 0, 0);
            acc = __builtin_amdgcn_mfma_f32_16x16x32_bf16(a[0][1], b21, acc, 0, 0, 0);
            acc = __builtin_amdgcn_mfma_f32_16x16x32_bf16(a[1][0], b10, acc, 0, 0, 0);
            acc = __builtin_amdgcn_mfma_f32_16x16x32_bf16(a[1][1], b11, acc, 0, 0, 0);
            acc = __builtin_amdgcn_mfma_f32_16x16x32_bf16(a[0][0], b10, acc, 0, 0, 0);
            acc = __builtin_amdgcn_mfma_f32_16x16x32_bf16(a[0][1], b11, acc, 0, 0, 0);

#pragma unroll
            for (int r = 0; r < 4; ++r) {
                float score = acc[r] - nrm;
                if (score > best[r]) { best[r] = score; bidx[r] = code; }
            }
        }

        // merge across 16 cols of each quad group; ties -> lowest index
#pragma unroll
        for (int off = 1; off < 16; off <<= 1)
#pragma unroll
            for (int r = 0; r < 4; ++r) {
                float os = __shfl_xor(best[r], off, 64);
                int   oi = __shfl_xor(bidx[r], off, 64);
                if (os > best[r] || (os == best[r] && oi < bidx[r])) {
                    best[r] = os; bidx[r] = oi;
                }
            }
        if (col == 0)
#pragma unroll
            for (int r = 0; r < 4; ++r) {
                sS[wave][quad * 4 + r] = best[r];
                sI[wave][quad * 4 + r] = bidx[r];
            }
        __syncthreads();

        // cross-wave merge (waves cover ascending code ranges)
        if (threadIdx.x < 16) {
            float bs = sS[0][threadIdx.x]; int bi = sI[0][threadIdx.x];
#pragma unroll
            for (int w = 1; w < 4; ++w) {
                float s2 = sS[w][threadIdx.x]; int i2 = sI[w][threadIdx.x];
                if (s2 > bs || (s2 == bs && i2 < bi)) { bs = s2; bi = i2; }
            }
            sI[0][threadIdx.x] = bi;
        }
        __syncthreads();

        // overwrite output for the tile's tokens (exact repair)
        {
            const int row  = threadIdx.x & 15;
            const int cb   = (threadIdx.x >> 4) * 4;
            const int tk2  = sTok[row];
            const int bb   = tk2 >> 12, hh = tk2 & 4095;
            const float* e = emb + sI[0][row] * 64;
            float* op = out + bb * 262144 + hh;
#pragma unroll
            for (int i = 0; i < 4; ++i)
                op[(cb + i) * 4096] = e[cb + i];
        }
        __syncthreads();                   // LDS reused next iteration
    }
}

// ---- fallback (proven Round-1 kernel; used only if ws is too small) ------
__global__ __launch_bounds__(256) void vq_fp32_kernel(
    const float* __restrict__ z, const float* __restrict__ emb,
    float* __restrict__ out)
{
    __shared__ float se[64 * 64];
    __shared__ float snorm[64];

    const int t  = blockIdx.x * 256 + threadIdx.x;
    const int b  = t >> 12;
    const int hw = t & 4095;
    const float* zt = z + (size_t)b * 262144 + hw;
    float zf[64];
#pragma unroll
    for (int c = 0; c < 64; ++c) zf[c] = zt[(size_t)c * 4096];

    float best = -3.4e38f;
    int   bestIdx = 0;
    for (int k0 = 0; k0 < 4096; k0 += 64) {
        __syncthreads();
        const float4* src = (const float4*)(emb + (size_t)k0 * 64);
        float4*       dst = (float4*)se;
#pragma unroll
        for (int i = 0; i < 4; ++i)
            dst[i * 256 + threadIdx.x] = src[i * 256 + threadIdx.x];
        __syncthreads();
        if (threadIdx.x < 64) {
            float s = 0.f;
#pragma unroll
            for (int c = 0; c < 64; ++c) {
                float v = se[threadIdx.x * 64 + c];
                s = fmaf(v, v, s);
            }
            snorm[threadIdx.x] = 0.5f * s;
        }
        __syncthreads();
#pragma unroll 4
        for (int kk = 0; kk < 64; ++kk) {
            float dot = 0.f;
#pragma unroll
            for (int c = 0; c < 64; ++c)
                dot = fmaf(zf[c], se[kk * 64 + c], dot);
            float score = dot - snorm[kk];
            if (score > best) { best = score; bestIdx = k0 + kk; }
        }
    }
    const float* e  = emb + (size_t)bestIdx * 64;
    float*       ot = out + (size_t)b * 262144 + hw;
#pragma unroll
    for (int c = 0; c < 64; ++c) ot[(size_t)c * 4096] = e[c];
}

extern "C" void kernel_launch(void* const* d_in, const int* in_sizes, int n_in,
                              void* d_out, int out_size, void* d_ws, size_t ws_size,
                              hipStream_t stream) {
    const float* z   = (const float*)d_in[0];
    const float* emb = (const float*)d_in[1];
    float*       out = (float*)d_out;

    if (ws_size < WS_NEEDED) {          // constant per session: graph-safe
        vq_fp32_kernel<<<256, 256, 0, stream>>>(z, emb, out);
        return;
    }

    unsigned short* wsB   = (unsigned short*)d_ws;
    float*          wsN   = (float*)((char*)d_ws + OFF_N);
    u32*            wsCnt = (u32*)((char*)d_ws + OFF_CNT);
    u32*            wsList= (u32*)((char*)d_ws + OFF_LIST);

    vq_pack_kernel<<<256, 384, 0, stream>>>(emb, wsB, wsN, wsCnt);
    vq_main_kernel<<<512, 256, 0, stream>>>(z, emb, wsB, wsN, wsCnt, wsList, out);
    vq_fix_kernel<<<64, 256, 0, stream>>>(z, emb, wsB, wsN, wsCnt, wsList, out);
}